// Round 7
// baseline (1369.529 us; speedup 1.0000x reference)
//
#include <hip/hip_runtime.h>

#define DEVFN static __device__ __forceinline__

namespace {
constexpr int Hc = 501, Gc = 517;
// ---- workspace float offsets ----
constexpr size_t OFF_WGP = 0;                               // [512][512] gate_w[:, :H] padded
constexpr size_t OFF_WMP = OFF_WGP + (size_t)512 * 512;     // map_w[:, :H]
constexpr size_t OFF_WHP = OFF_WMP + (size_t)512 * 512;     // w_hh packed [i][3][512]
constexpr size_t OFF_WHV = OFF_WHP + (size_t)512 * 1536;    // (dead)
constexpr size_t OFF_WHJ = OFF_WHV + (size_t)2048 * 512;    // (dead)
constexpr size_t OFF_WAV = OFF_WHJ + (size_t)2048 * 512;    // (dead)
constexpr size_t OFF_GCOL= OFF_WAV + (size_t)1024 * 512;    // gate_w[:, H+j] [512][16]
constexpr size_t OFF_MCOL= OFF_GCOL + (size_t)512 * 16;
constexpr size_t OFF_GI  = OFF_MCOL + (size_t)512 * 16;     // [16][16][1536]
constexpr size_t OFF_GS0 = OFF_GI  + (size_t)16 * 16 * 1536;// [16][512]
constexpr size_t OFF_HSEQ= OFF_GS0 + (size_t)16 * 512;      // [16 b][136 slot][512]  (NaN-init)
constexpr size_t OFF_HINS= OFF_HSEQ+ (size_t)16 * 136 * 512;// [120 slot][16 b][512]  (NaN-init)
constexpr size_t OFF_TBUF= OFF_HINS+ (size_t)120 * 16 * 512;// [16 b][16 idx][1024]
constexpr size_t WS_FLOATS=OFF_TBUF+ (size_t)16 * 16 * 1024;
constexpr size_t N_FLG   = (size_t)8 * 256 * 32;            // (dead region, kept for layout)
constexpr size_t WS_NEED = (WS_FLOATS + N_FLG + 512 + 64) * 4;

// ---- k1 LDS float offsets ----
constexpr int SM_WHH = 0;       // 16*3*512 = 24576
constexpr int SM_ST  = 24576;   // 2*512 staging
constexpr int SM_QM  = 25600;   // [b*2+qm][j<15][ig]  2*2*15*16 = 960
constexpr int SM_PS  = 26560;   // [b][ig][vj] 512
constexpr int SM_GC  = 27072;   // [q/m][ig][j] 512
constexpr int SM_GIL = 27584;   // [b][r][ig] 96
constexpr int SM_BHH = 27680;   // [r][ig] 48
constexpr int SM_GB  = 27728;   // 16
constexpr int SM_MB  = 27744;   // 16
constexpr int SM_DEP = 27760;   // [b][j] 32
constexpr int SM_TOT = 27792;
// ---- k2 LDS float offsets ----
constexpr int F_BHJ = 8192;     // [j<15][128]
constexpr int F_RED = 10112;    // 260
constexpr int F_TOT = 10376;
} // namespace

DEVFN float sigf(float x)  { return 1.0f / (1.0f + __expf(-x)); }
DEVFN float tanhf_(float x){ float e2 = __expf(2.0f * x); return 1.0f - 2.0f / (e2 + 1.0f); }
DEVFN void  stgf(float* p, float v) { __hip_atomic_store(p, v, __ATOMIC_RELAXED, __HIP_MEMORY_SCOPE_AGENT); }
DEVFN size_t hslotf(int b, int slot) { return OFF_HSEQ + ((size_t)b * 136 + slot) * 512; }
DEVFN int trif(int idx) { return idx * (idx + 1) / 2; }

struct KArgs {
  const float* in[21];
  float* out;
  float* wsf;
};

DEVFN float4 maskpad(float4 v, int k4) {
  if (k4 == 125) { v.y = 0.f; v.z = 0.f; v.w = 0.f; }
  else if (k4 > 125) { v.x = v.y = v.z = v.w = 0.f; }
  return v;
}

// ================= init kernel ==========
__global__ __launch_bounds__(256) void k0_init(KArgs a) {
  const float* z    = a.in[0];  const float* enc  = a.in[2];
  const float* lin1w= a.in[3];  const float* lin1b= a.in[4];
  const float* gatew= a.in[13]; const float* mapw = a.in[15];
  const float* wih  = a.in[17]; const float* bih  = a.in[18];
  const float* whh  = a.in[19];
  float* wsf = a.wsf;
  const int gtid = blockIdx.x * 256 + threadIdx.x;
  const int NTH = 256 * 256;

  for (size_t t = gtid; t < (size_t)512 * 512; t += NTH) {
    int i = t >> 9, k = t & 511;
    bool ok = (i < Hc && k < Hc);
    wsf[OFF_WGP + t] = ok ? gatew[(size_t)i * Gc + k] : 0.f;
    wsf[OFF_WMP + t] = ok ? mapw [(size_t)i * Gc + k] : 0.f;
  }
  for (size_t t = gtid; t < (size_t)512 * 1536; t += NTH) {
    int i = t / 1536, rk = t % 1536, r = rk >> 9, k = rk & 511;
    wsf[OFF_WHP + t] = (i < Hc && k < Hc) ? whh[((size_t)r * Hc + i) * Hc + k] : 0.f;
  }
  for (size_t t = gtid; t < (size_t)512 * 16; t += NTH) {
    int i = t >> 4, j = t & 15;
    wsf[OFF_GCOL + t] = (i < Hc) ? gatew[(size_t)i * Gc + Hc + j] : 0.f;
    wsf[OFF_MCOL + t] = (i < Hc) ? mapw [(size_t)i * Gc + Hc + j] : 0.f;
  }
  for (size_t t = gtid; t < (size_t)16 * 16 * 1503; t += NTH) {
    int r = t % 1503; size_t bi = t / 1503;
    float acc = bih[r];
    const float* x = enc + bi * 10;
    const float* w = wih + (size_t)r * 10;
    #pragma unroll
    for (int c = 0; c < 10; ++c) acc = fmaf(w[c], x[c], acc);
    wsf[OFF_GI + bi * 1536 + r] = acc;
  }
  for (size_t t = gtid; t < (size_t)16 * 512; t += NTH) {
    int b = t >> 9, i = t & 511;
    float v = 0.f;
    if (i < Hc) {
      float acc = lin1b[i];
      const float* zz = z + (size_t)b * 56;
      const float* w  = lin1w + (size_t)i * 56;
      for (int k = 0; k < 56; ++k) acc = fmaf(w[k], zz[k], acc);
      v = acc;
    }
    wsf[OFF_GS0 + t] = v;
  }
  // NaN-poison all exchange slots (HSEQ + HINS): data-as-flag polling.
  {
    unsigned* p = (unsigned*)(wsf + OFF_HSEQ);
    const size_t n = OFF_TBUF - OFF_HSEQ;   // 2,097,152 dwords
    for (size_t t = gtid; t < n; t += NTH) p[t] = 0x7FC00000u;
  }
  for (size_t t = gtid; t < 4096; t += NTH) a.out[t] = 0.f;   // gen_dep zero (atomics)
  unsigned* FLG = (unsigned*)a.wsf + WS_FLOATS;
  for (size_t t = gtid; t < 512; t += NTH) FLG[N_FLG + t] = 0u;  // F1F + spare
}

// ================= k1: persistent scan — dataflow via NaN-poll (no barriers) ==========
__global__ __launch_bounds__(256, 1) void k1_scan(KArgs a) {
  const int blk = blockIdx.x, tid = threadIdx.x;
  const int g = blk >> 5, m = blk & 31;        // group (2 batches), member
  const int ig = tid >> 4, l = tid & 15;       // i-subgroup, k-lane
  const int i = m * 16 + ig;                   // owned row
  float* wsf = a.wsf;
  const float* dep  = a.in[1];
  const float* gateb= a.in[14]; const float* mapb = a.in[16];
  const float* bhh  = a.in[20];

  __shared__ float smem[SM_TOT];

  {
    float4* d = (float4*)smem;
    const float4* s = ((const float4*)(wsf + OFF_WHP)) + (size_t)m * 6144;
    for (int t = tid; t < 6144; t += 256) d[t] = s[t];
    for (int t = tid; t < 512; t += 256) {
      int q = t >> 8, r2 = t & 255, ii = r2 >> 4, j = r2 & 15;
      smem[SM_GC + t] = wsf[(q ? OFF_MCOL : OFF_GCOL) + (size_t)(m * 16 + ii) * 16 + j];
    }
    if (tid < 16) {
      int iG = m * 16 + tid;
      smem[SM_GB + tid] = (iG < Hc) ? gateb[iG] : 0.f;
      smem[SM_MB + tid] = (iG < Hc) ? mapb[iG]  : 0.f;
    }
    if (tid < 48) {
      int r = tid >> 4, ii = tid & 15, iG = m * 16 + ii;
      smem[SM_BHH + tid] = (iG < Hc) ? bhh[r * Hc + iG] : 0.f;
    }
  }
  float4 wgr[8], wmr[8];
  {
    const float4* pg = ((const float4*)(wsf + OFF_WGP)) + (size_t)i * 128;
    const float4* pm = ((const float4*)(wsf + OFF_WMP)) + (size_t)i * 128;
    #pragma unroll
    for (int t = 0; t < 8; ++t) { wgr[t] = pg[t * 16 + l]; wmr[t] = pm[t * 16 + l]; }
  }

  // poll-stage: thread t owns one float4 of the 2-batch exchange (t<128: b0, else b1).
  // Spins until all 4 dwords are non-NaN (producers never produce NaN), then stages to LDS.
  auto pollst = [&](size_t o0, size_t o1) {
    size_t base = (tid < 128) ? o0 : o1;
    int idx = (tid & 127) * 4;
    const volatile float* s = (const volatile float*)(wsf + base) + idx;
    float x, y, zv, w;
    for (;;) {
      x = s[0]; y = s[1]; zv = s[2]; w = s[3];
      if (!(x != x || y != y || zv != zv || w != w)) break;
      __builtin_amdgcn_s_sleep(1);
    }
    float* d = smem + SM_ST + (tid < 128 ? 0 : 512) + idx;
    d[0] = x; d[1] = y; d[2] = zv; d[3] = w;
  };
  auto stagegi = [&](int index) {
    if (tid >= 64 && tid < 160) {
      int t = tid - 64, b = t / 48, r = (t / 16) % 3, ii = t & 15, iG = m * 16 + ii;
      smem[SM_GIL + (b * 3 + r) * 16 + ii] =
        (iG < Hc) ? wsf[OFF_GI + ((size_t)(2 * g + b) * 16 + index) * 1536 + (size_t)r * Hc + iG] : 0.f;
    }
  };
  auto s1core = [&](float& aq0, float& am0, float& aq1, float& am1) {
    const float4* h0 = (const float4*)(smem + SM_ST);
    const float4* h1 = (const float4*)(smem + SM_ST + 512);
    float q0 = 0.f, m0 = 0.f, q1 = 0.f, m1 = 0.f;
    #pragma unroll
    for (int t = 0; t < 8; ++t) {
      int k4 = t * 16 + l;
      float4 a0 = h0[k4], a1 = h1[k4];
      q0 = fmaf(wgr[t].x, a0.x, q0); q0 = fmaf(wgr[t].y, a0.y, q0);
      q0 = fmaf(wgr[t].z, a0.z, q0); q0 = fmaf(wgr[t].w, a0.w, q0);
      m0 = fmaf(wmr[t].x, a0.x, m0); m0 = fmaf(wmr[t].y, a0.y, m0);
      m0 = fmaf(wmr[t].z, a0.z, m0); m0 = fmaf(wmr[t].w, a0.w, m0);
      q1 = fmaf(wgr[t].x, a1.x, q1); q1 = fmaf(wgr[t].y, a1.y, q1);
      q1 = fmaf(wgr[t].z, a1.z, q1); q1 = fmaf(wgr[t].w, a1.w, q1);
      m1 = fmaf(wmr[t].x, a1.x, m1); m1 = fmaf(wmr[t].y, a1.y, m1);
      m1 = fmaf(wmr[t].z, a1.z, m1); m1 = fmaf(wmr[t].w, a1.w, m1);
    }
    q0 += __shfl_xor(q0, 1); q0 += __shfl_xor(q0, 2); q0 += __shfl_xor(q0, 4); q0 += __shfl_xor(q0, 8);
    m0 += __shfl_xor(m0, 1); m0 += __shfl_xor(m0, 2); m0 += __shfl_xor(m0, 4); m0 += __shfl_xor(m0, 8);
    q1 += __shfl_xor(q1, 1); q1 += __shfl_xor(q1, 2); q1 += __shfl_xor(q1, 4); q1 += __shfl_xor(q1, 8);
    m1 += __shfl_xor(m1, 1); m1 += __shfl_xor(m1, 2); m1 += __shfl_xor(m1, 4); m1 += __shfl_xor(m1, 8);
    aq0 = q0; am0 = m0; aq1 = q1; am1 = m1;
  };
  auto s2core = [&](int dstSlot) {
    const float4* W  = ((const float4*)smem) + ig * 384;
    const float4* h0 = (const float4*)(smem + SM_ST);
    const float4* h1 = (const float4*)(smem + SM_ST + 512);
    float gr0 = 0.f, gz0 = 0.f, gn0 = 0.f, gr1 = 0.f, gz1 = 0.f, gn1 = 0.f;
    #pragma unroll
    for (int t = 0; t < 8; ++t) {
      int k4 = t * 16 + l;
      float4 hv0 = h0[k4], hv1 = h1[k4];
      float4 a0 = W[k4], a1 = W[128 + k4], a2 = W[256 + k4];
      gr0 = fmaf(a0.x, hv0.x, gr0); gr0 = fmaf(a0.y, hv0.y, gr0); gr0 = fmaf(a0.z, hv0.z, gr0); gr0 = fmaf(a0.w, hv0.w, gr0);
      gz0 = fmaf(a1.x, hv0.x, gz0); gz0 = fmaf(a1.y, hv0.y, gz0); gz0 = fmaf(a1.z, hv0.z, gz0); gz0 = fmaf(a1.w, hv0.w, gz0);
      gn0 = fmaf(a2.x, hv0.x, gn0); gn0 = fmaf(a2.y, hv0.y, gn0); gn0 = fmaf(a2.z, hv0.z, gn0); gn0 = fmaf(a2.w, hv0.w, gn0);
      gr1 = fmaf(a0.x, hv1.x, gr1); gr1 = fmaf(a0.y, hv1.y, gr1); gr1 = fmaf(a0.z, hv1.z, gr1); gr1 = fmaf(a0.w, hv1.w, gr1);
      gz1 = fmaf(a1.x, hv1.x, gz1); gz1 = fmaf(a1.y, hv1.y, gz1); gz1 = fmaf(a1.z, hv1.z, gz1); gz1 = fmaf(a1.w, hv1.w, gz1);
      gn1 = fmaf(a2.x, hv1.x, gn1); gn1 = fmaf(a2.y, hv1.y, gn1); gn1 = fmaf(a2.z, hv1.z, gn1); gn1 = fmaf(a2.w, hv1.w, gn1);
    }
    gr0 += __shfl_xor(gr0, 1); gr0 += __shfl_xor(gr0, 2); gr0 += __shfl_xor(gr0, 4); gr0 += __shfl_xor(gr0, 8);
    gz0 += __shfl_xor(gz0, 1); gz0 += __shfl_xor(gz0, 2); gz0 += __shfl_xor(gz0, 4); gz0 += __shfl_xor(gz0, 8);
    gn0 += __shfl_xor(gn0, 1); gn0 += __shfl_xor(gn0, 2); gn0 += __shfl_xor(gn0, 4); gn0 += __shfl_xor(gn0, 8);
    gr1 += __shfl_xor(gr1, 1); gr1 += __shfl_xor(gr1, 2); gr1 += __shfl_xor(gr1, 4); gr1 += __shfl_xor(gr1, 8);
    gz1 += __shfl_xor(gz1, 1); gz1 += __shfl_xor(gz1, 2); gz1 += __shfl_xor(gz1, 4); gz1 += __shfl_xor(gz1, 8);
    gn1 += __shfl_xor(gn1, 1); gn1 += __shfl_xor(gn1, 2); gn1 += __shfl_xor(gn1, 4); gn1 += __shfl_xor(gn1, 8);
    if (l < 2) {
      int b = l;
      float gr = l ? gr1 : gr0, gz = l ? gz1 : gz0, gn = l ? gn1 : gn0;
      float h  = smem[SM_ST + b * 512 + i];
      float rr = sigf(smem[SM_GIL + (b * 3 + 0) * 16 + ig] + gr + smem[SM_BHH + 0 + ig]);
      float uu = sigf(smem[SM_GIL + (b * 3 + 1) * 16 + ig] + gz + smem[SM_BHH + 16 + ig]);
      float nn = tanhf_(smem[SM_GIL + (b * 3 + 2) * 16 + ig] + rr * (gn + smem[SM_BHH + 32 + ig]));
      float v = (1.f - uu) * nn + uu * h;
      if (i >= Hc) v = 0.f;
      stgf(wsf + hslotf(2 * g + b, dstSlot) + i, v);
    }
  };

  // ===== phase 0: hv(idx0) = GRU(x0, gs0)  (GS0 from k0, poll passes instantly) =====
  __syncthreads();
  pollst(OFF_GS0 + (size_t)(2 * g) * 512, OFF_GS0 + (size_t)(2 * g + 1) * 512);
  stagegi(0);
  __syncthreads();
  s2core(0);

  // ===== scan =====
  for (int index = 1; index < 16; ++index) {
    // ---- phase A ----
    __syncthreads();
    pollst(hslotf(2 * g,     trif(index - 1) + index - 1),
           hslotf(2 * g + 1, trif(index - 1) + index - 1));
    if (tid < 32) {
      int b = tid >> 4, j = tid & 15;
      smem[SM_DEP + b * 16 + j] = dep[((size_t)(2 * g + b) * 16 + index) * 16 + j];
    }
    stagegi(index);
    __syncthreads();
    {
      float aq0, am0, aq1, am1;
      s1core(aq0, am0, aq1, am1);
      if (l < 2) {
        float aq = l ? aq1 : aq0, am = l ? am1 : am0;
        smem[SM_QM + ((l * 2 + 0) * 15 + (index - 1)) * 16 + ig] = aq + smem[SM_GC + ig * 16 + (index - 1)];
        smem[SM_QM + ((l * 2 + 1) * 15 + (index - 1)) * 16 + ig] = am + smem[SM_GC + 256 + ig * 16 + (index - 1)];
      }
    }
    __syncthreads();
    if (l < 2) {
      float acc = 0.f, gb = smem[SM_GB + ig], mb = smem[SM_MB + ig];
      for (int j = 15; j >= 0; --j) {
        if (j != index) {
          float aa = smem[SM_DEP + l * 16 + j];
          float q, mm;
          if (j < index) { q = smem[SM_QM + ((l * 2 + 0) * 15 + j) * 16 + ig];
                           mm = smem[SM_QM + ((l * 2 + 1) * 15 + j) * 16 + ig]; }
          else           { q = smem[SM_GC + ig * 16 + j];
                           mm = smem[SM_GC + 256 + ig * 16 + j]; }
          float sg = sigf(fmaf(aa, q, gb));
          acc = fmaf(aa * sg, fmaf(aa, mm, mb), acc);
        }
        smem[SM_PS + (l * 16 + ig) * 16 + j] = acc;
      }
    } else if (l < 4) {
      int b = l - 2;
      float rr = sigf(smem[SM_GIL + (b * 3 + 0) * 16 + ig] + smem[SM_BHH + 0 + ig]);
      float uu = sigf(smem[SM_GIL + (b * 3 + 1) * 16 + ig] + smem[SM_BHH + 16 + ig]);
      float nn = tanhf_(smem[SM_GIL + (b * 3 + 2) * 16 + ig] + rr * smem[SM_BHH + 32 + ig]);
      float v = (1.f - uu) * nn;
      if (i >= Hc) v = 0.f;
      stgf(wsf + hslotf(2 * g + b, trif(index) + 0) + i, v);
    }
    __syncthreads();
    if (l < 2) {
      int b = l;
      float gb = smem[SM_GB + ig], mb = smem[SM_MB + ig];
      float aI = smem[SM_DEP + b * 16 + index];
      float Qi = smem[SM_GC + ig * 16 + index], Mi = smem[SM_GC + 256 + ig * 16 + index];
      float f = aI * sigf(fmaf(aI, Qi, gb)) * fmaf(aI, Mi, mb);
      float v = smem[SM_PS + (b * 16 + ig) * 16 + (index - 1)] + f;
      if (i >= Hc) v = 0.f;
      stgf(wsf + OFF_HINS + ((size_t)(index * (index - 1) / 2 + 0) * 16 + (2 * g + b)) * 512 + i, v);
    }

    for (int s = 0; s < index; ++s) {
      // ---- S2(s) ----
      __syncthreads();
      pollst(OFF_HINS + ((size_t)(index * (index - 1) / 2 + s) * 16 + (2 * g + 0)) * 512,
             OFF_HINS + ((size_t)(index * (index - 1) / 2 + s) * 16 + (2 * g + 1)) * 512);
      __syncthreads();
      s2core(trif(index) + s + 1);
      if (s + 1 < index) {
        // ---- S1(s+1) ----
        int ss = s + 1, vj = index - 1 - ss;
        __syncthreads();
        pollst(hslotf(2 * g, trif(index) + ss), hslotf(2 * g + 1, trif(index) + ss));
        __syncthreads();
        {
          float aq0, am0, aq1, am1;
          s1core(aq0, am0, aq1, am1);
          if (l < 2) {
            int b = l;
            float aq = l ? aq1 : aq0, am = l ? am1 : am0;
            float gb = smem[SM_GB + ig], mb = smem[SM_MB + ig];
            float aI = smem[SM_DEP + b * 16 + index];
            float Qi = aq + smem[SM_GC + ig * 16 + index];
            float Mi = am + smem[SM_GC + 256 + ig * 16 + index];
            float f = aI * sigf(fmaf(aI, Qi, gb)) * fmaf(aI, Mi, mb);
            float v = smem[SM_PS + (b * 16 + ig) * 16 + vj] + f;
            if (i >= Hc) v = 0.f;
            stgf(wsf + OFF_HINS + ((size_t)(index * (index - 1) / 2 + ss) * 16 + (2 * g + b)) * 512 + i, v);
          }
        }
      }
    }
  }
}

// ================= k2: deferred edges + node encodings (unchanged from R6) ==========
__global__ __launch_bounds__(256, 1) void k2_fin(KArgs a) {
  const int blk = blockIdx.x, tid = threadIdx.x;
  float* wsf = a.wsf;
  unsigned* FLG = (unsigned*)a.wsf + WS_FLOATS;
  unsigned* F1F = FLG + N_FLG;
  const float* ae1w = a.in[9];
  const float* av1w = a.in[5];

  __shared__ float smem[F_TOT];
  const int b = blk >> 4, rs = blk & 15;
  const int il = tid >> 3, l8 = tid & 7;
  float4* lds4 = (float4*)smem;

  for (int t = tid; t < 2048; t += 256) {
    int j = t >> 7, k4 = t & 127;
    float4 v = {0.f, 0.f, 0.f, 0.f};
    if (j < 15) v = maskpad(((const float4*)(wsf + hslotf(b, trif(j) + j)))[k4], k4);
    lds4[t] = v;
  }
  __syncthreads();
  {
    const int rbase = rs * 126 + il * 4;
    for (int half = 0; half < 2; ++half) {
      int jbase = half * 8;
      float acc[4][8];
      #pragma unroll
      for (int q = 0; q < 4; ++q)
        #pragma unroll
        for (int j = 0; j < 8; ++j) acc[q][j] = 0.f;
      for (int s = 0; s < 63; ++s) {
        int k = s * 8 + l8;
        if (k < 501) {
          float w[4];
          #pragma unroll
          for (int q = 0; q < 4; ++q)
            w[q] = (rbase + q < 2004) ? ae1w[(size_t)(rbase + q) * 1002 + 501 + k] : 0.f;
          float hv[8];
          #pragma unroll
          for (int j = 0; j < 8; ++j) hv[j] = smem[(jbase + j) * 512 + k];
          #pragma unroll
          for (int q = 0; q < 4; ++q)
            #pragma unroll
            for (int j = 0; j < 8; ++j) acc[q][j] = fmaf(w[q], hv[j], acc[q][j]);
        }
      }
      #pragma unroll
      for (int q = 0; q < 4; ++q) {
        bool rowok = (il * 4 + q < 126) && (rbase + q < 2004);
        #pragma unroll
        for (int j = 0; j < 8; ++j) {
          float v = acc[q][j];
          v += __shfl_xor(v, 1); v += __shfl_xor(v, 2); v += __shfl_xor(v, 4);
          if (l8 == 0 && rowok && (jbase + j) < 15)
            smem[F_BHJ + (jbase + j) * 128 + il * 4 + q] = v;
        }
      }
    }
  }
  __syncthreads();
  for (int t = tid; t < 2048; t += 256) {
    int idx = t >> 7, k4 = t & 127;
    const float4* src = (idx == 0)
      ? ((const float4*)(wsf + OFF_GS0 + (size_t)b * 512))
      : ((const float4*)(wsf + hslotf(b, trif(idx - 1) + idx - 1)));
    lds4[t] = maskpad(src[k4], k4);
  }
  __syncthreads();
  {
    const float* av1b = a.in[6];
    const int rbase = rs * 63 + il * 2;
    for (int half = 0; half < 2; ++half) {
      int jbase = half * 8;
      float acc[2][8];
      #pragma unroll
      for (int q = 0; q < 2; ++q)
        #pragma unroll
        for (int j = 0; j < 8; ++j) acc[q][j] = 0.f;
      for (int s = 0; s < 63; ++s) {
        int k = s * 8 + l8;
        if (k < 501) {
          float w[2];
          #pragma unroll
          for (int q = 0; q < 2; ++q)
            w[q] = (rbase + q < 1002) ? av1w[(size_t)(rbase + q) * 501 + k] : 0.f;
          float hv[8];
          #pragma unroll
          for (int j = 0; j < 8; ++j) hv[j] = smem[(jbase + j) * 512 + k];
          #pragma unroll
          for (int q = 0; q < 2; ++q)
            #pragma unroll
            for (int j = 0; j < 8; ++j) acc[q][j] = fmaf(w[q], hv[j], acc[q][j]);
        }
      }
      #pragma unroll
      for (int q = 0; q < 2; ++q) {
        int r = rbase + q;
        bool rowok = (il * 2 + q < 63) && (r < 1002);
        float b1 = rowok ? av1b[r] : 0.f;
        #pragma unroll
        for (int j = 0; j < 8; ++j) {
          float v = acc[q][j];
          v += __shfl_xor(v, 1); v += __shfl_xor(v, 2); v += __shfl_xor(v, 4);
          if (l8 == 0 && rowok)
            stgf(wsf + OFF_TBUF + ((size_t)b * 16 + jbase + j) * 1024 + r, fmaxf(v + b1, 0.f));
        }
      }
    }
  }
  __syncthreads();
  if (tid == 0)
    __hip_atomic_store(F1F + b * 16 + rs, 1u, __ATOMIC_RELAXED, __HIP_MEMORY_SCOPE_AGENT);

  const float* ae1b = a.in[10]; const float* ae2w = a.in[11]; const float* ae2b = a.in[12];
  const int rbase = rs * 126 + il * 4;
  for (int chunk = 0; chunk < 15; ++chunk) {
    int idxs[8], vjs[8]; bool tval[8];
    #pragma unroll
    for (int j = 0; j < 8; ++j) {
      int e = chunk * 8 + j;
      if (e < 120) {
        int ix = 1, rem = e;
        while (rem >= ix) { rem -= ix; ++ix; }
        idxs[j] = ix; vjs[j] = rem; tval[j] = true;
      } else { idxs[j] = 1; vjs[j] = 0; tval[j] = false; }
    }
    __syncthreads();
    for (int t = tid; t < 1024; t += 256) {
      int sl = t >> 7, k4 = t & 127;
      int sE = idxs[sl] - 1 - vjs[sl];
      lds4[t] = maskpad(((const float4*)(wsf + hslotf(b, trif(idxs[sl]) + sE)))[k4], k4);
    }
    __syncthreads();
    float part[8];
    #pragma unroll
    for (int j = 0; j < 8; ++j) part[j] = 0.f;
    float acc[4][8];
    #pragma unroll
    for (int q = 0; q < 4; ++q)
      #pragma unroll
      for (int j = 0; j < 8; ++j) acc[q][j] = 0.f;
    for (int s = 0; s < 63; ++s) {
      int k = s * 8 + l8;
      if (k < 501) {
        float w[4];
        #pragma unroll
        for (int q = 0; q < 4; ++q)
          w[q] = (rbase + q < 2004) ? ae1w[(size_t)(rbase + q) * 1002 + k] : 0.f;
        float hv[8];
        #pragma unroll
        for (int j = 0; j < 8; ++j) hv[j] = smem[j * 512 + k];
        #pragma unroll
        for (int q = 0; q < 4; ++q)
          #pragma unroll
          for (int j = 0; j < 8; ++j) acc[q][j] = fmaf(w[q], hv[j], acc[q][j]);
      }
    }
    #pragma unroll
    for (int q = 0; q < 4; ++q) {
      int r = rbase + q;
      bool rowok = (il * 4 + q < 126) && (r < 2004);
      float aer = rowok ? ae2w[r] : 0.f;
      float b1r = rowok ? ae1b[r] : 0.f;
      #pragma unroll
      for (int j = 0; j < 8; ++j) {
        float v = acc[q][j];
        v += __shfl_xor(v, 1); v += __shfl_xor(v, 2); v += __shfl_xor(v, 4);
        if (l8 == 0 && rowok && tval[j]) {
          float bh = smem[F_BHJ + vjs[j] * 128 + il * 4 + q];
          part[j] = fmaf(aer, fmaxf(v + bh + b1r, 0.f), part[j]);
        }
      }
    }
    if (l8 == 0) {
      #pragma unroll
      for (int j = 0; j < 8; ++j) smem[F_RED + il * 8 + j] = part[j];
    }
    __syncthreads();
    if (tid < 8) {
      float v = 0.f;
      for (int q = 0; q < 32; ++q) v += smem[F_RED + q * 8 + tid];
      if (rs == 0) v += ae2b[0];
      if (tval[tid])
        atomicAdd(a.out + ((size_t)b * 16 + idxs[tid]) * 16 + vjs[tid], v);
    }
    __syncthreads();
  }
  if (tid < 16) {
    unsigned* p = F1F + b * 16 + tid;
    while (__hip_atomic_load(p, __ATOMIC_RELAXED, __HIP_MEMORY_SCOPE_AGENT) != 1u)
      __builtin_amdgcn_s_sleep(2);
  }
  __syncthreads();
  {
    const float* av2w = a.in[7]; const float* av2b = a.in[8];
    const float* tb = wsf + OFF_TBUF + ((size_t)b * 16 + rs) * 1024;
    float accn[10];
    #pragma unroll
    for (int c = 0; c < 10; ++c) accn[c] = 0.f;
    for (int r = tid; r < 1002; r += 256) {
      float tv = tb[r];
      #pragma unroll
      for (int c = 0; c < 10; ++c) accn[c] = fmaf(av2w[(size_t)c * 1002 + r], tv, accn[c]);
    }
    #pragma unroll
    for (int c = 0; c < 10; ++c) {
      float v = accn[c];
      for (int m2 = 1; m2 < 64; m2 <<= 1) v += __shfl_xor(v, m2);
      if ((tid & 63) == 0) smem[F_RED + (tid >> 6) * 10 + c] = v;
    }
    __syncthreads();
    if (tid == 0) {
      for (int c = 0; c < 10; ++c) {
        float v = av2b[c] + smem[F_RED + c] + smem[F_RED + 10 + c] + smem[F_RED + 20 + c] + smem[F_RED + 30 + c];
        stgf(a.out + 4096 + ((size_t)b * 16 + rs) * 10 + c, v);
      }
    }
  }
}

extern "C" void kernel_launch(void* const* d_in, const int* in_sizes, int n_in,
                              void* d_out, int out_size, void* d_ws, size_t ws_size,
                              hipStream_t stream) {
  (void)in_sizes; (void)n_in; (void)out_size;
  if (ws_size < WS_NEED) return;   // fail loudly via validation
  KArgs a;
  for (int k = 0; k < 21; ++k) a.in[k] = (const float*)d_in[k];
  a.out = (float*)d_out;
  a.wsf = (float*)d_ws;
  k0_init<<<256, 256, 0, stream>>>(a);
  k1_scan<<<256, 256, 0, stream>>>(a);
  k2_fin <<<256, 256, 0, stream>>>(a);
}

// Round 9
// 1138.001 us; speedup vs baseline: 1.2035x; 1.2035x over previous
//
#include <hip/hip_runtime.h>

#define DEVFN static __device__ __forceinline__

namespace {
constexpr int Hc = 501, Gc = 517;
// ---- workspace float offsets (weight regions dead; exchanges + GS0/TBUF live) ----
constexpr size_t OFF_GS0 = (size_t)7 * 1024 * 1024;         // [16][512]
constexpr size_t OFF_HSEQ= OFF_GS0 + (size_t)16 * 512;      // [16 b][136 slot][512]
constexpr size_t OFF_HINS= OFF_HSEQ+ (size_t)16 * 136 * 512;// [120 slot][16 b][512]
constexpr size_t OFF_TBUF= OFF_HINS+ (size_t)120 * 16 * 512;// [16 b][16 idx][1024]
constexpr size_t WS_FLOATS=OFF_TBUF+ (size_t)16 * 16 * 1024;
constexpr size_t N_FLG   = (size_t)8 * 256 * 32;            // [group][pid][member]
constexpr size_t WS_NEED = (WS_FLOATS + N_FLG + 512 + 64) * 4;

// ---- k1 LDS float offsets ----
constexpr int SM_WHH = 0;       // 16*1536 = 24576
constexpr int SM_ST  = 24576;   // 2*512 staging
constexpr int SM_QM  = 25600;   // 960
constexpr int SM_PS  = 26560;   // 512
constexpr int SM_GC  = 27072;   // 512
constexpr int SM_GIS = 27584;   // [b][idx][r][ig] 1536
constexpr int SM_BHH = 29120;   // 48
constexpr int SM_GB  = 29168;   // 16
constexpr int SM_MB  = 29184;   // 16
constexpr int SM_DEP = 29200;   // 32
constexpr int SM_TOT = 29232;
// ---- k2 LDS float offsets ----
constexpr int F_BHJ = 8192;     // [j<15][128]
constexpr int F_RED = 10112;    // 260
constexpr int F_TOT = 10376;
} // namespace

DEVFN float sigf(float x)  { return 1.0f / (1.0f + __expf(-x)); }
DEVFN float tanhf_(float x){ float e2 = __expf(2.0f * x); return 1.0f - 2.0f / (e2 + 1.0f); }
DEVFN void  stgf(float* p, float v) { __hip_atomic_store(p, v, __ATOMIC_RELAXED, __HIP_MEMORY_SCOPE_AGENT); }
DEVFN size_t hslotf(int b, int slot) { return OFF_HSEQ + ((size_t)b * 136 + slot) * 512; }
DEVFN int trif(int idx) { return idx * (idx + 1) / 2; }
DEVFN int mini(int a, int b) { return a < b ? a : b; }

struct KArgs {
  const float* in[21];
  float* out;
  float* wsf;
};

DEVFN float4 maskpad(float4 v, int k4) {
  if (k4 == 125) { v.y = 0.f; v.z = 0.f; v.w = 0.f; }
  else if (k4 > 125) { v.x = v.y = v.z = v.w = 0.f; }
  return v;
}

// ================= k0: zero out + flags only ==========
__global__ __launch_bounds__(256) void k0_init(KArgs a) {
  const int gtid = blockIdx.x * 256 + threadIdx.x;
  const int NTH = 64 * 256;
  for (size_t t = gtid; t < 4096; t += NTH) a.out[t] = 0.f;   // gen_dep zero (atomics)
  unsigned* FLG = (unsigned*)a.wsf + WS_FLOATS;
  for (size_t t = gtid; t < N_FLG + 512; t += NTH) FLG[t] = 0u;
}

// ================= k1: persistent scan — self-staged weights from cached d_in ==========
__global__ __launch_bounds__(256, 1) void k1_scan(KArgs a) {
  const int blk = blockIdx.x, tid = threadIdx.x;
  const int g = blk >> 5, m = blk & 31;        // group (2 batches), member
  const int ig = tid >> 4, l = tid & 15;       // i-subgroup, k-lane
  const int i = m * 16 + ig;                   // owned row
  float* wsf = a.wsf;
  unsigned* FLG = (unsigned*)a.wsf + WS_FLOATS;
  const float* z    = a.in[0];  const float* dep  = a.in[1];  const float* enc = a.in[2];
  const float* lin1w= a.in[3];  const float* lin1b= a.in[4];
  const float* gatew= a.in[13]; const float* gateb= a.in[14];
  const float* mapw = a.in[15]; const float* mapb = a.in[16];
  const float* wih  = a.in[17]; const float* bih  = a.in[18];
  const float* whh  = a.in[19]; const float* bhh  = a.in[20];

  __shared__ float smem[SM_TOT];
  int pid = 0;

  // ---- init: Whh slice (transposed read, coalesced in k) from cached d_in ----
  for (int t = tid; t < 16 * 1536; t += 256) {
    int ig2 = t / 1536, rk = t % 1536, r = rk >> 9, k = rk & 511;
    int i2 = m * 16 + ig2;
    smem[t] = (i2 < Hc && k < Hc) ? whh[((size_t)(r * Hc + i2)) * Hc + k] : 0.f;
  }
  // gate/map trailing cols for own rows
  for (int t = tid; t < 512; t += 256) {
    int q = t >> 8, r2 = t & 255, ii = r2 >> 4, j = r2 & 15;
    int iG = m * 16 + ii;
    const float* W = q ? mapw : gatew;
    smem[SM_GC + t] = (iG < Hc) ? W[(size_t)iG * Gc + Hc + j] : 0.f;
  }
  // gi slice: [b][idx][r][ig]
  for (int t = tid; t < 1536; t += 256) {
    int ig3 = t & 15, u = t >> 4, r = u % 3, v2 = u / 3, idx = v2 & 15, b = v2 >> 4;
    int iG = m * 16 + ig3;
    float val = 0.f;
    if (iG < Hc) {
      int rr = r * Hc + iG;
      const float* x = enc + ((size_t)(2 * g + b) * 16 + idx) * 10;
      float acc = bih[rr];
      const float* w = wih + (size_t)rr * 10;
      #pragma unroll
      for (int c = 0; c < 10; ++c) acc = fmaf(w[c], x[c], acc);
      val = acc;
    }
    smem[SM_GIS + t] = val;
  }
  if (tid < 16) {
    int iG = m * 16 + tid;
    smem[SM_GB + tid] = (iG < Hc) ? gateb[iG] : 0.f;
    smem[SM_MB + tid] = (iG < Hc) ? mapb[iG]  : 0.f;
  }
  if (tid >= 64 && tid < 112) {
    int t = tid - 64, r = t >> 4, ii = t & 15, iG = m * 16 + ii;
    smem[SM_BHH + t] = (iG < Hc) ? bhh[r * Hc + iG] : 0.f;
  }
  // Wg/Wm row fragments from d_in: lane l owns float4s {t*16+l}
  float4 wgr[8], wmr[8];
  #pragma unroll
  for (int t = 0; t < 8; ++t) {
    int kb = (t * 16 + l) * 4;
    float gv[4], mv[4];
    #pragma unroll
    for (int c = 0; c < 4; ++c) {
      int kk = kb + c;
      bool ok = (i < Hc && kk < Hc);
      gv[c] = ok ? gatew[(size_t)i * Gc + kk] : 0.f;
      mv[c] = ok ? mapw [(size_t)i * Gc + kk] : 0.f;
    }
    wgr[t] = make_float4(gv[0], gv[1], gv[2], gv[3]);
    wmr[t] = make_float4(mv[0], mv[1], mv[2], mv[3]);
  }
  // gs0 (full, redundant per block) into SM_ST; member 0 publishes to ws for k2
  for (int t = tid; t < 1024; t += 256) {
    int b = t >> 9, ii = t & 511;
    float v = 0.f;
    if (ii < Hc) {
      float acc = lin1b[ii];
      const float* zz = z + (size_t)(2 * g + b) * 56;
      const float* w  = lin1w + (size_t)ii * 56;
      for (int k = 0; k < 56; ++k) acc = fmaf(w[k], zz[k], acc);
      v = acc;
    }
    smem[SM_ST + t] = v;
    if (m == 0) stgf(wsf + OFF_GS0 + (size_t)2 * g * 512 + t, v);
  }
  __syncthreads();

  // ---- group barrier: 32 parallel sentinel stores; 32 lanes poll ----
  auto flagbar = [&]() {
    __syncthreads();
    if (tid == 0)
      __hip_atomic_store(FLG + ((size_t)g * 256 + pid) * 32 + m, (unsigned)(pid + 1),
                         __ATOMIC_RELAXED, __HIP_MEMORY_SCOPE_AGENT);
    if (tid < 32) {
      unsigned* p = FLG + ((size_t)g * 256 + pid) * 32 + tid;
      while (__hip_atomic_load(p, __ATOMIC_RELAXED, __HIP_MEMORY_SCOPE_AGENT) != (unsigned)(pid + 1))
        __builtin_amdgcn_s_sleep(2);
    }
    __syncthreads();
    ++pid;
  };

  auto stage2v = [&](size_t o0, size_t o1) {
    float4* d = (float4*)(smem + SM_ST);
    if (tid < 128) d[tid] = ((const float4*)(wsf + o0))[tid];
    else           d[tid] = ((const float4*)(wsf + o1))[tid - 128];
  };
  auto s1core = [&](float& aq0, float& am0, float& aq1, float& am1) {
    const float4* h0 = (const float4*)(smem + SM_ST);
    const float4* h1 = (const float4*)(smem + SM_ST + 512);
    float q0 = 0.f, m0 = 0.f, q1 = 0.f, m1 = 0.f;
    #pragma unroll
    for (int t = 0; t < 8; ++t) {
      int k4 = t * 16 + l;
      float4 a0 = h0[k4], a1 = h1[k4];
      q0 = fmaf(wgr[t].x, a0.x, q0); q0 = fmaf(wgr[t].y, a0.y, q0);
      q0 = fmaf(wgr[t].z, a0.z, q0); q0 = fmaf(wgr[t].w, a0.w, q0);
      m0 = fmaf(wmr[t].x, a0.x, m0); m0 = fmaf(wmr[t].y, a0.y, m0);
      m0 = fmaf(wmr[t].z, a0.z, m0); m0 = fmaf(wmr[t].w, a0.w, m0);
      q1 = fmaf(wgr[t].x, a1.x, q1); q1 = fmaf(wgr[t].y, a1.y, q1);
      q1 = fmaf(wgr[t].z, a1.z, q1); q1 = fmaf(wgr[t].w, a1.w, q1);
      m1 = fmaf(wmr[t].x, a1.x, m1); m1 = fmaf(wmr[t].y, a1.y, m1);
      m1 = fmaf(wmr[t].z, a1.z, m1); m1 = fmaf(wmr[t].w, a1.w, m1);
    }
    q0 += __shfl_xor(q0, 1); q0 += __shfl_xor(q0, 2); q0 += __shfl_xor(q0, 4); q0 += __shfl_xor(q0, 8);
    m0 += __shfl_xor(m0, 1); m0 += __shfl_xor(m0, 2); m0 += __shfl_xor(m0, 4); m0 += __shfl_xor(m0, 8);
    q1 += __shfl_xor(q1, 1); q1 += __shfl_xor(q1, 2); q1 += __shfl_xor(q1, 4); q1 += __shfl_xor(q1, 8);
    m1 += __shfl_xor(m1, 1); m1 += __shfl_xor(m1, 2); m1 += __shfl_xor(m1, 4); m1 += __shfl_xor(m1, 8);
    aq0 = q0; am0 = m0; aq1 = q1; am1 = m1;
  };
  auto s2core = [&](int index, int dstSlot) {
    const float4* W  = ((const float4*)smem) + ig * 384;
    const float4* h0 = (const float4*)(smem + SM_ST);
    const float4* h1 = (const float4*)(smem + SM_ST + 512);
    float gr0 = 0.f, gz0 = 0.f, gn0 = 0.f, gr1 = 0.f, gz1 = 0.f, gn1 = 0.f;
    #pragma unroll
    for (int t = 0; t < 8; ++t) {
      int k4 = t * 16 + l;
      float4 hv0 = h0[k4], hv1 = h1[k4];
      float4 a0 = W[k4], a1 = W[128 + k4], a2 = W[256 + k4];
      gr0 = fmaf(a0.x, hv0.x, gr0); gr0 = fmaf(a0.y, hv0.y, gr0); gr0 = fmaf(a0.z, hv0.z, gr0); gr0 = fmaf(a0.w, hv0.w, gr0);
      gz0 = fmaf(a1.x, hv0.x, gz0); gz0 = fmaf(a1.y, hv0.y, gz0); gz0 = fmaf(a1.z, hv0.z, gz0); gz0 = fmaf(a1.w, hv0.w, gz0);
      gn0 = fmaf(a2.x, hv0.x, gn0); gn0 = fmaf(a2.y, hv0.y, gn0); gn0 = fmaf(a2.z, hv0.z, gn0); gn0 = fmaf(a2.w, hv0.w, gn0);
      gr1 = fmaf(a0.x, hv1.x, gr1); gr1 = fmaf(a0.y, hv1.y, gr1); gr1 = fmaf(a0.z, hv1.z, gr1); gr1 = fmaf(a0.w, hv1.w, gr1);
      gz1 = fmaf(a1.x, hv1.x, gz1); gz1 = fmaf(a1.y, hv1.y, gz1); gz1 = fmaf(a1.z, hv1.z, gz1); gz1 = fmaf(a1.w, hv1.w, gz1);
      gn1 = fmaf(a2.x, hv1.x, gn1); gn1 = fmaf(a2.y, hv1.y, gn1); gn1 = fmaf(a2.z, hv1.z, gn1); gn1 = fmaf(a2.w, hv1.w, gn1);
    }
    gr0 += __shfl_xor(gr0, 1); gr0 += __shfl_xor(gr0, 2); gr0 += __shfl_xor(gr0, 4); gr0 += __shfl_xor(gr0, 8);
    gz0 += __shfl_xor(gz0, 1); gz0 += __shfl_xor(gz0, 2); gz0 += __shfl_xor(gz0, 4); gz0 += __shfl_xor(gz0, 8);
    gn0 += __shfl_xor(gn0, 1); gn0 += __shfl_xor(gn0, 2); gn0 += __shfl_xor(gn0, 4); gn0 += __shfl_xor(gn0, 8);
    gr1 += __shfl_xor(gr1, 1); gr1 += __shfl_xor(gr1, 2); gr1 += __shfl_xor(gr1, 4); gr1 += __shfl_xor(gr1, 8);
    gz1 += __shfl_xor(gz1, 1); gz1 += __shfl_xor(gz1, 2); gz1 += __shfl_xor(gz1, 4); gz1 += __shfl_xor(gz1, 8);
    gn1 += __shfl_xor(gn1, 1); gn1 += __shfl_xor(gn1, 2); gn1 += __shfl_xor(gn1, 4); gn1 += __shfl_xor(gn1, 8);
    if (l < 2) {
      int b = l;
      float gr = l ? gr1 : gr0, gz = l ? gz1 : gz0, gn = l ? gn1 : gn0;
      float h  = smem[SM_ST + b * 512 + i];
      const int gb2 = SM_GIS + ((b * 16 + index) * 3) * 16 + ig;
      float rr = sigf(smem[gb2 + 0]  + gr + smem[SM_BHH + 0 + ig]);
      float uu = sigf(smem[gb2 + 16] + gz + smem[SM_BHH + 16 + ig]);
      float nn = tanhf_(smem[gb2 + 32] + rr * (gn + smem[SM_BHH + 32 + ig]));
      float v = (1.f - uu) * nn + uu * h;
      if (i >= Hc) v = 0.f;
      stgf(wsf + hslotf(2 * g + b, dstSlot) + i, v);
    }
  };

  // ===== phase 0: hv(idx0) = GRU(x0, gs0) — gs0 already in SM_ST =====
  s2core(0, 0);
  flagbar();

  // ===== scan =====
  for (int index = 1; index < 16; ++index) {
    stage2v(hslotf(2 * g,     trif(index - 1) + index - 1),
            hslotf(2 * g + 1, trif(index - 1) + index - 1));
    if (tid < 32) {
      int b = tid >> 4, j = tid & 15;
      smem[SM_DEP + b * 16 + j] = dep[((size_t)(2 * g + b) * 16 + index) * 16 + j];
    }
    __syncthreads();
    {
      float aq0, am0, aq1, am1;
      s1core(aq0, am0, aq1, am1);
      if (l < 2) {
        float aq = l ? aq1 : aq0, am = l ? am1 : am0;
        smem[SM_QM + ((l * 2 + 0) * 15 + (index - 1)) * 16 + ig] = aq + smem[SM_GC + ig * 16 + (index - 1)];
        smem[SM_QM + ((l * 2 + 1) * 15 + (index - 1)) * 16 + ig] = am + smem[SM_GC + 256 + ig * 16 + (index - 1)];
      }
    }
    __syncthreads();
    if (l < 2) {               // PS backward cumsum, b = l
      float acc = 0.f, gb = smem[SM_GB + ig], mb = smem[SM_MB + ig];
      for (int j = 15; j >= 0; --j) {
        if (j != index) {
          float aa = smem[SM_DEP + l * 16 + j];
          float q, mm;
          if (j < index) { q = smem[SM_QM + ((l * 2 + 0) * 15 + j) * 16 + ig];
                           mm = smem[SM_QM + ((l * 2 + 1) * 15 + j) * 16 + ig]; }
          else           { q = smem[SM_GC + ig * 16 + j];
                           mm = smem[SM_GC + 256 + ig * 16 + j]; }
          float sg = sigf(fmaf(aa, q, gb));
          acc = fmaf(aa * sg, fmaf(aa, mm, mb), acc);
        }
        smem[SM_PS + (l * 16 + ig) * 16 + j] = acc;
      }
    } else if (l < 4) {        // hv0 = gru(x,0), b = l-2
      int b = l - 2;
      const int gb2 = SM_GIS + ((b * 16 + index) * 3) * 16 + ig;
      float rr = sigf(smem[gb2 + 0]  + smem[SM_BHH + 0 + ig]);
      float uu = sigf(smem[gb2 + 16] + smem[SM_BHH + 16 + ig]);
      float nn = tanhf_(smem[gb2 + 32] + rr * smem[SM_BHH + 32 + ig]);
      float v = (1.f - uu) * nn;
      if (i >= Hc) v = 0.f;
      stgf(wsf + hslotf(2 * g + b, trif(index) + 0) + i, v);
    }
    __syncthreads();
    if (l < 2) {               // h_in(s=0)
      int b = l;
      float gb = smem[SM_GB + ig], mb = smem[SM_MB + ig];
      float aI = smem[SM_DEP + b * 16 + index];
      float Qi = smem[SM_GC + ig * 16 + index], Mi = smem[SM_GC + 256 + ig * 16 + index];
      float f = aI * sigf(fmaf(aI, Qi, gb)) * fmaf(aI, Mi, mb);
      float v = smem[SM_PS + (b * 16 + ig) * 16 + (index - 1)] + f;
      if (i >= Hc) v = 0.f;
      stgf(wsf + OFF_HINS + ((size_t)(index * (index - 1) / 2 + 0) * 16 + (2 * g + b)) * 512 + i, v);
    }
    flagbar();

    for (int s = 0; s < index; ++s) {
      stage2v(OFF_HINS + ((size_t)(index * (index - 1) / 2 + s) * 16 + (2 * g + 0)) * 512,
              OFF_HINS + ((size_t)(index * (index - 1) / 2 + s) * 16 + (2 * g + 1)) * 512);
      __syncthreads();
      s2core(index, trif(index) + s + 1);
      flagbar();
      if (s + 1 < index) {
        int ss = s + 1, vj = index - 1 - ss;
        stage2v(hslotf(2 * g, trif(index) + ss), hslotf(2 * g + 1, trif(index) + ss));
        __syncthreads();
        {
          float aq0, am0, aq1, am1;
          s1core(aq0, am0, aq1, am1);
          if (l < 2) {
            int b = l;
            float aq = l ? aq1 : aq0, am = l ? am1 : am0;
            float gb = smem[SM_GB + ig], mb = smem[SM_MB + ig];
            float aI = smem[SM_DEP + b * 16 + index];
            float Qi = aq + smem[SM_GC + ig * 16 + index];
            float Mi = am + smem[SM_GC + 256 + ig * 16 + index];
            float f = aI * sigf(fmaf(aI, Qi, gb)) * fmaf(aI, Mi, mb);
            float v = smem[SM_PS + (b * 16 + ig) * 16 + vj] + f;
            if (i >= Hc) v = 0.f;
            stgf(wsf + OFF_HINS + ((size_t)(index * (index - 1) / 2 + ss) * 16 + (2 * g + b)) * 512 + i, v);
          }
        }
        flagbar();
      }
    }
  }
}

// ================= k2: deferred edges + node encodings — pipelined, per-row clamped loads ==========
__global__ __launch_bounds__(256, 1) void k2_fin(KArgs a) {
  const int blk = blockIdx.x, tid = threadIdx.x;
  float* wsf = a.wsf;
  unsigned* FLG = (unsigned*)a.wsf + WS_FLOATS;
  unsigned* F1F = FLG + N_FLG;
  const float* ae1w = a.in[9];   // [2004][1002] cached
  const float* av1w = a.in[5];   // [1002][501]

  __shared__ float smem[F_TOT];
  const int b = blk >> 4, rs = blk & 15;
  const int il = tid >> 3, l8 = tid & 7;
  float4* lds4 = (float4*)smem;

  // ---- F1a staging: 16 nhs finals (row 15 zero) ----
  for (int t = tid; t < 2048; t += 256) {
    int j = t >> 7, k4 = t & 127;
    float4 v = {0.f, 0.f, 0.f, 0.f};
    if (j < 15) v = maskpad(((const float4*)(wsf + hslotf(b, trif(j) + j)))[k4], k4);
    lds4[t] = v;
  }
  __syncthreads();
  // ---- prefetch F1b staging into registers (hidden under F1a compute) ----
  float4 pfb[8];
  #pragma unroll
  for (int p = 0; p < 8; ++p) {
    int fidx = p * 256 + tid, idx = fidx >> 7, k4 = fidx & 127;
    const float4* src = (idx == 0)
      ? ((const float4*)(wsf + OFF_GS0 + (size_t)b * 512))
      : ((const float4*)(wsf + hslotf(b, trif(idx - 1) + idx - 1)));
    pfb[p] = maskpad(src[k4], k4);
  }
  // ---- F1a compute: Bhj = ae1w[:,501:] @ nhs_j ----
  {
    const int rbase = rs * 126 + il * 4;
    int rq[4];
    #pragma unroll
    for (int q = 0; q < 4; ++q) rq[q] = mini(rbase + q, 2003);   // per-row clamp: valid rows keep own weights
    for (int half = 0; half < 2; ++half) {
      int jbase = half * 8;
      float acc[4][8];
      #pragma unroll
      for (int q = 0; q < 4; ++q)
        #pragma unroll
        for (int j = 0; j < 8; ++j) acc[q][j] = 0.f;
      for (int s = 0; s < 63; ++s) {
        int k = s * 8 + l8;
        int kc = (k > 500) ? 500 : k;                // hv[k>=501]==0 kills garbage
        float w[4];
        #pragma unroll
        for (int q = 0; q < 4; ++q) w[q] = ae1w[(size_t)rq[q] * 1002 + 501 + kc];
        float hv[8];
        #pragma unroll
        for (int j = 0; j < 8; ++j) hv[j] = smem[(jbase + j) * 512 + k];
        #pragma unroll
        for (int q = 0; q < 4; ++q)
          #pragma unroll
          for (int j = 0; j < 8; ++j) acc[q][j] = fmaf(w[q], hv[j], acc[q][j]);
      }
      #pragma unroll
      for (int q = 0; q < 4; ++q) {
        bool rowok = (il * 4 + q < 126) && (rbase + q < 2004);
        #pragma unroll
        for (int j = 0; j < 8; ++j) {
          float v = acc[q][j];
          v += __shfl_xor(v, 1); v += __shfl_xor(v, 2); v += __shfl_xor(v, 4);
          if (l8 == 0 && rowok && (jbase + j) < 15)
            smem[F_BHJ + (jbase + j) * 128 + il * 4 + q] = v;
        }
      }
    }
  }
  __syncthreads();
  // ---- F1b staging from registers ----
  #pragma unroll
  for (int p = 0; p < 8; ++p) lds4[p * 256 + tid] = pfb[p];
  __syncthreads();
  // ---- F1b compute: TBUF = relu(av1w @ gs-list + b) ----
  {
    const float* av1b = a.in[6];
    const int rbase = rs * 63 + il * 2;
    int rq[2];
    #pragma unroll
    for (int q = 0; q < 2; ++q) rq[q] = mini(rbase + q, 1001);
    for (int half = 0; half < 2; ++half) {
      int jbase = half * 8;
      float acc[2][8];
      #pragma unroll
      for (int q = 0; q < 2; ++q)
        #pragma unroll
        for (int j = 0; j < 8; ++j) acc[q][j] = 0.f;
      for (int s = 0; s < 63; ++s) {
        int k = s * 8 + l8;
        int kc = (k > 500) ? 500 : k;
        float w[2];
        #pragma unroll
        for (int q = 0; q < 2; ++q) w[q] = av1w[(size_t)rq[q] * 501 + kc];
        float hv[8];
        #pragma unroll
        for (int j = 0; j < 8; ++j) hv[j] = smem[(jbase + j) * 512 + k];
        #pragma unroll
        for (int q = 0; q < 2; ++q)
          #pragma unroll
          for (int j = 0; j < 8; ++j) acc[q][j] = fmaf(w[q], hv[j], acc[q][j]);
      }
      #pragma unroll
      for (int q = 0; q < 2; ++q) {
        int r = rbase + q;
        bool rowok = (il * 2 + q < 63) && (r < 1002);
        float b1 = rowok ? av1b[r] : 0.f;
        #pragma unroll
        for (int j = 0; j < 8; ++j) {
          float v = acc[q][j];
          v += __shfl_xor(v, 1); v += __shfl_xor(v, 2); v += __shfl_xor(v, 4);
          if (l8 == 0 && rowok)
            stgf(wsf + OFF_TBUF + ((size_t)b * 16 + jbase + j) * 1024 + r, fmaxf(v + b1, 0.f));
        }
      }
    }
  }
  __syncthreads();
  if (tid == 0)
    __hip_atomic_store(F1F + b * 16 + rs, 1u, __ATOMIC_RELAXED, __HIP_MEMORY_SCOPE_AGENT);

  // ---- F2: 120 edges, double-buffered chunk staging ----
  const float* ae1b = a.in[10]; const float* ae2w = a.in[11]; const float* ae2b = a.in[12];
  const int rbase = rs * 126 + il * 4;
  int rq[4];
  #pragma unroll
  for (int q = 0; q < 4; ++q) rq[q] = mini(rbase + q, 2003);
  auto decode = [&](int chunk, int* idxs, int* vjs, bool* tval) {
    #pragma unroll
    for (int j = 0; j < 8; ++j) {
      int e = chunk * 8 + j;
      if (e < 120) {
        int ix = 1, rem = e;
        while (rem >= ix) { rem -= ix; ++ix; }
        idxs[j] = ix; vjs[j] = rem; tval[j] = true;
      } else { idxs[j] = 1; vjs[j] = 0; tval[j] = false; }
    }
  };
  // stage chunk 0 into buffer A
  {
    int idxs[8], vjs[8]; bool tval[8];
    decode(0, idxs, vjs, tval);
    for (int t = tid; t < 1024; t += 256) {
      int sl = t >> 7, k4 = t & 127;
      int sE = idxs[sl] - 1 - vjs[sl];
      lds4[t] = maskpad(((const float4*)(wsf + hslotf(b, trif(idxs[sl]) + sE)))[k4], k4);
    }
  }
  __syncthreads();
  int cur = 0;
  for (int chunk = 0; chunk < 15; ++chunk) {
    int idxs[8], vjs[8]; bool tval[8];
    decode(chunk, idxs, vjs, tval);
    // prefetch next chunk into registers
    float4 pf[4];
    if (chunk < 14) {
      int nidxs[8], nvjs[8]; bool ntval[8];
      decode(chunk + 1, nidxs, nvjs, ntval);
      #pragma unroll
      for (int p = 0; p < 4; ++p) {
        int fidx = p * 256 + tid, sl = fidx >> 7, k4 = fidx & 127;
        int sE = nidxs[sl] - 1 - nvjs[sl];
        pf[p] = maskpad(((const float4*)(wsf + hslotf(b, trif(nidxs[sl]) + sE)))[k4], k4);
      }
    }
    // compute from buffer `cur`
    const float* hbuf = smem + cur * 4096;
    float acc[4][8];
    #pragma unroll
    for (int q = 0; q < 4; ++q)
      #pragma unroll
      for (int j = 0; j < 8; ++j) acc[q][j] = 0.f;
    for (int s = 0; s < 63; ++s) {
      int k = s * 8 + l8;
      int kc = (k > 500) ? 500 : k;
      float w[4];
      #pragma unroll
      for (int q = 0; q < 4; ++q) w[q] = ae1w[(size_t)rq[q] * 1002 + kc];
      float hv[8];
      #pragma unroll
      for (int j = 0; j < 8; ++j) hv[j] = hbuf[j * 512 + k];
      #pragma unroll
      for (int q = 0; q < 4; ++q)
        #pragma unroll
        for (int j = 0; j < 8; ++j) acc[q][j] = fmaf(w[q], hv[j], acc[q][j]);
    }
    float part[8];
    #pragma unroll
    for (int j = 0; j < 8; ++j) part[j] = 0.f;
    #pragma unroll
    for (int q = 0; q < 4; ++q) {
      int r = rbase + q;
      bool rowok = (il * 4 + q < 126) && (r < 2004);
      float aer = rowok ? ae2w[r] : 0.f;
      float b1r = rowok ? ae1b[r] : 0.f;
      #pragma unroll
      for (int j = 0; j < 8; ++j) {
        float v = acc[q][j];
        v += __shfl_xor(v, 1); v += __shfl_xor(v, 2); v += __shfl_xor(v, 4);
        if (l8 == 0 && rowok && tval[j]) {
          float bh = smem[F_BHJ + vjs[j] * 128 + il * 4 + q];
          part[j] = fmaf(aer, fmaxf(v + bh + b1r, 0.f), part[j]);
        }
      }
    }
    if (l8 == 0) {
      #pragma unroll
      for (int j = 0; j < 8; ++j) smem[F_RED + il * 8 + j] = part[j];
    }
    __syncthreads();
    if (tid < 8) {
      float v = 0.f;
      for (int q = 0; q < 32; ++q) v += smem[F_RED + q * 8 + tid];
      if (rs == 0) v += ae2b[0];
      if (tval[tid])
        atomicAdd(a.out + ((size_t)b * 16 + idxs[tid]) * 16 + vjs[tid], v);
    }
    __syncthreads();
    if (chunk < 14) {
      #pragma unroll
      for (int p = 0; p < 4; ++p) lds4[(1 - cur) * 1024 + p * 256 + tid] = pf[p];
      cur = 1 - cur;
      __syncthreads();
    }
  }
  // ---- F3: gen_node_encoding[(b, rs)] ----
  if (tid < 16) {
    unsigned* p = F1F + b * 16 + tid;
    while (__hip_atomic_load(p, __ATOMIC_RELAXED, __HIP_MEMORY_SCOPE_AGENT) != 1u)
      __builtin_amdgcn_s_sleep(2);
  }
  __syncthreads();
  {
    const float* av2w = a.in[7]; const float* av2b = a.in[8];
    const float* tb = wsf + OFF_TBUF + ((size_t)b * 16 + rs) * 1024;
    float accn[10];
    #pragma unroll
    for (int c = 0; c < 10; ++c) accn[c] = 0.f;
    for (int r = tid; r < 1002; r += 256) {
      float tv = tb[r];
      #pragma unroll
      for (int c = 0; c < 10; ++c) accn[c] = fmaf(av2w[(size_t)c * 1002 + r], tv, accn[c]);
    }
    #pragma unroll
    for (int c = 0; c < 10; ++c) {
      float v = accn[c];
      for (int m2 = 1; m2 < 64; m2 <<= 1) v += __shfl_xor(v, m2);
      if ((tid & 63) == 0) smem[F_RED + (tid >> 6) * 10 + c] = v;
    }
    __syncthreads();
    if (tid == 0) {
      for (int c = 0; c < 10; ++c) {
        float v = av2b[c] + smem[F_RED + c] + smem[F_RED + 10 + c] + smem[F_RED + 20 + c] + smem[F_RED + 30 + c];
        stgf(a.out + 4096 + ((size_t)b * 16 + rs) * 10 + c, v);
      }
    }
  }
}

extern "C" void kernel_launch(void* const* d_in, const int* in_sizes, int n_in,
                              void* d_out, int out_size, void* d_ws, size_t ws_size,
                              hipStream_t stream) {
  (void)in_sizes; (void)n_in; (void)out_size;
  if (ws_size < WS_NEED) return;   // fail loudly via validation
  KArgs a;
  for (int k = 0; k < 21; ++k) a.in[k] = (const float*)d_in[k];
  a.out = (float*)d_out;
  a.wsf = (float*)d_ws;
  k0_init<<<64, 256, 0, stream>>>(a);
  k1_scan<<<256, 256, 0, stream>>>(a);
  k2_fin <<<256, 256, 0, stream>>>(a);
}

// Round 10
// 1094.493 us; speedup vs baseline: 1.2513x; 1.0398x over previous
//
#include <hip/hip_runtime.h>

#define DEVFN static __device__ __forceinline__

namespace {
constexpr int Hc = 501, Gc = 517;
// ---- workspace float offsets ----
constexpr size_t OFF_GS0 = (size_t)7 * 1024 * 1024;         // [16][512]
constexpr size_t OFF_HSEQ= OFF_GS0 + (size_t)16 * 512;      // [16 b][136 slot][512]
constexpr size_t OFF_HINS= OFF_HSEQ+ (size_t)16 * 136 * 512;// [120 slot][16 b][512]
constexpr size_t OFF_TBUF= OFF_HINS+ (size_t)120 * 16 * 512;// [16 b][16 idx][1024]
constexpr size_t WS_FLOATS=OFF_TBUF+ (size_t)16 * 16 * 1024;
constexpr size_t N_FLG   = (size_t)8 * 256 * 32;            // [group][pid][member]
constexpr size_t WS_NEED = (WS_FLOATS + N_FLG + 512 + 64) * 4;

// ---- k1 LDS float offsets ----
constexpr int SM_WHH = 0;       // 16*1536 = 24576
constexpr int SM_ST  = 24576;   // 2*512 staging
constexpr int SM_QM  = 25600;   // 960
constexpr int SM_PS  = 26560;   // 512
constexpr int SM_GC  = 27072;   // 512
constexpr int SM_GIS = 27584;   // [b][idx][r][ig] 1536
constexpr int SM_BHH = 29120;   // 48
constexpr int SM_GB  = 29168;   // 16
constexpr int SM_MB  = 29184;   // 16
constexpr int SM_DEP = 29200;   // 32
constexpr int SM_TOT = 29232;
// ---- k2 LDS float offsets ----
constexpr int F_BHJ = 8192;     // [j<15][64]
constexpr int F_RED = 10112;    // 260
constexpr int F_TOT = 10376;
} // namespace

DEVFN float sigf(float x)  { return 1.0f / (1.0f + __expf(-x)); }
DEVFN float tanhf_(float x){ float e2 = __expf(2.0f * x); return 1.0f - 2.0f / (e2 + 1.0f); }
DEVFN void  stgf(float* p, float v) { __hip_atomic_store(p, v, __ATOMIC_RELAXED, __HIP_MEMORY_SCOPE_AGENT); }
DEVFN size_t hslotf(int b, int slot) { return OFF_HSEQ + ((size_t)b * 136 + slot) * 512; }
DEVFN int trif(int idx) { return idx * (idx + 1) / 2; }
DEVFN int mini(int a, int b) { return a < b ? a : b; }

struct KArgs {
  const float* in[21];
  float* out;
  float* wsf;
};

DEVFN float4 maskpad(float4 v, int k4) {
  if (k4 == 125) { v.y = 0.f; v.z = 0.f; v.w = 0.f; }
  else if (k4 > 125) { v.x = v.y = v.z = v.w = 0.f; }
  return v;
}

// ================= k0: zero out + flags only ==========
__global__ __launch_bounds__(256) void k0_init(KArgs a) {
  const int gtid = blockIdx.x * 256 + threadIdx.x;
  const int NTH = 64 * 256;
  for (size_t t = gtid; t < 4096; t += NTH) a.out[t] = 0.f;   // gen_dep zero (atomics)
  unsigned* FLG = (unsigned*)a.wsf + WS_FLOATS;
  for (size_t t = gtid; t < N_FLG + 512; t += NTH) FLG[t] = 0u;
}

// ================= k1: persistent scan — self-staged weights from cached d_in ==========
__global__ __launch_bounds__(256, 1) void k1_scan(KArgs a) {
  const int blk = blockIdx.x, tid = threadIdx.x;
  const int g = blk >> 5, m = blk & 31;        // group (2 batches), member
  const int ig = tid >> 4, l = tid & 15;       // i-subgroup, k-lane
  const int i = m * 16 + ig;                   // owned row
  float* wsf = a.wsf;
  unsigned* FLG = (unsigned*)a.wsf + WS_FLOATS;
  const float* z    = a.in[0];  const float* dep  = a.in[1];  const float* enc = a.in[2];
  const float* lin1w= a.in[3];  const float* lin1b= a.in[4];
  const float* gatew= a.in[13]; const float* gateb= a.in[14];
  const float* mapw = a.in[15]; const float* mapb = a.in[16];
  const float* wih  = a.in[17]; const float* bih  = a.in[18];
  const float* whh  = a.in[19]; const float* bhh  = a.in[20];

  __shared__ float smem[SM_TOT];
  int pid = 0;

  // ---- init: Whh slice (transposed read, coalesced in k) from cached d_in ----
  for (int t = tid; t < 16 * 1536; t += 256) {
    int ig2 = t / 1536, rk = t % 1536, r = rk >> 9, k = rk & 511;
    int i2 = m * 16 + ig2;
    smem[t] = (i2 < Hc && k < Hc) ? whh[((size_t)(r * Hc + i2)) * Hc + k] : 0.f;
  }
  // gate/map trailing cols for own rows
  for (int t = tid; t < 512; t += 256) {
    int q = t >> 8, r2 = t & 255, ii = r2 >> 4, j = r2 & 15;
    int iG = m * 16 + ii;
    const float* W = q ? mapw : gatew;
    smem[SM_GC + t] = (iG < Hc) ? W[(size_t)iG * Gc + Hc + j] : 0.f;
  }
  // gi slice: [b][idx][r][ig]
  for (int t = tid; t < 1536; t += 256) {
    int ig3 = t & 15, u = t >> 4, r = u % 3, v2 = u / 3, idx = v2 & 15, b = v2 >> 4;
    int iG = m * 16 + ig3;
    float val = 0.f;
    if (iG < Hc) {
      int rr = r * Hc + iG;
      const float* x = enc + ((size_t)(2 * g + b) * 16 + idx) * 10;
      float acc = bih[rr];
      const float* w = wih + (size_t)rr * 10;
      #pragma unroll
      for (int c = 0; c < 10; ++c) acc = fmaf(w[c], x[c], acc);
      val = acc;
    }
    smem[SM_GIS + t] = val;
  }
  if (tid < 16) {
    int iG = m * 16 + tid;
    smem[SM_GB + tid] = (iG < Hc) ? gateb[iG] : 0.f;
    smem[SM_MB + tid] = (iG < Hc) ? mapb[iG]  : 0.f;
  }
  if (tid >= 64 && tid < 112) {
    int t = tid - 64, r = t >> 4, ii = t & 15, iG = m * 16 + ii;
    smem[SM_BHH + t] = (iG < Hc) ? bhh[r * Hc + iG] : 0.f;
  }
  // Wg/Wm row fragments from d_in: lane l owns float4s {t*16+l}
  float4 wgr[8], wmr[8];
  #pragma unroll
  for (int t = 0; t < 8; ++t) {
    int kb = (t * 16 + l) * 4;
    float gv[4], mv[4];
    #pragma unroll
    for (int c = 0; c < 4; ++c) {
      int kk = kb + c;
      bool ok = (i < Hc && kk < Hc);
      gv[c] = ok ? gatew[(size_t)i * Gc + kk] : 0.f;
      mv[c] = ok ? mapw [(size_t)i * Gc + kk] : 0.f;
    }
    wgr[t] = make_float4(gv[0], gv[1], gv[2], gv[3]);
    wmr[t] = make_float4(mv[0], mv[1], mv[2], mv[3]);
  }
  // gs0 (full, redundant per block) into SM_ST; member 0 publishes to ws for k2
  for (int t = tid; t < 1024; t += 256) {
    int b = t >> 9, ii = t & 511;
    float v = 0.f;
    if (ii < Hc) {
      float acc = lin1b[ii];
      const float* zz = z + (size_t)(2 * g + b) * 56;
      const float* w  = lin1w + (size_t)ii * 56;
      for (int k = 0; k < 56; ++k) acc = fmaf(w[k], zz[k], acc);
      v = acc;
    }
    smem[SM_ST + t] = v;
    if (m == 0) stgf(wsf + OFF_GS0 + (size_t)2 * g * 512 + t, v);
  }
  __syncthreads();

  // ---- group barrier: 32 parallel sentinel stores; 32 lanes poll ----
  auto flagbar = [&]() {
    __syncthreads();
    if (tid == 0)
      __hip_atomic_store(FLG + ((size_t)g * 256 + pid) * 32 + m, (unsigned)(pid + 1),
                         __ATOMIC_RELAXED, __HIP_MEMORY_SCOPE_AGENT);
    if (tid < 32) {
      unsigned* p = FLG + ((size_t)g * 256 + pid) * 32 + tid;
      while (__hip_atomic_load(p, __ATOMIC_RELAXED, __HIP_MEMORY_SCOPE_AGENT) != (unsigned)(pid + 1))
        __builtin_amdgcn_s_sleep(2);
    }
    __syncthreads();
    ++pid;
  };

  auto stage2v = [&](size_t o0, size_t o1) {
    float4* d = (float4*)(smem + SM_ST);
    if (tid < 128) d[tid] = ((const float4*)(wsf + o0))[tid];
    else           d[tid] = ((const float4*)(wsf + o1))[tid - 128];
  };
  auto s1core = [&](float& aq0, float& am0, float& aq1, float& am1) {
    const float4* h0 = (const float4*)(smem + SM_ST);
    const float4* h1 = (const float4*)(smem + SM_ST + 512);
    float q0 = 0.f, m0 = 0.f, q1 = 0.f, m1 = 0.f;
    #pragma unroll
    for (int t = 0; t < 8; ++t) {
      int k4 = t * 16 + l;
      float4 a0 = h0[k4], a1 = h1[k4];
      q0 = fmaf(wgr[t].x, a0.x, q0); q0 = fmaf(wgr[t].y, a0.y, q0);
      q0 = fmaf(wgr[t].z, a0.z, q0); q0 = fmaf(wgr[t].w, a0.w, q0);
      m0 = fmaf(wmr[t].x, a0.x, m0); m0 = fmaf(wmr[t].y, a0.y, m0);
      m0 = fmaf(wmr[t].z, a0.z, m0); m0 = fmaf(wmr[t].w, a0.w, m0);
      q1 = fmaf(wgr[t].x, a1.x, q1); q1 = fmaf(wgr[t].y, a1.y, q1);
      q1 = fmaf(wgr[t].z, a1.z, q1); q1 = fmaf(wgr[t].w, a1.w, q1);
      m1 = fmaf(wmr[t].x, a1.x, m1); m1 = fmaf(wmr[t].y, a1.y, m1);
      m1 = fmaf(wmr[t].z, a1.z, m1); m1 = fmaf(wmr[t].w, a1.w, m1);
    }
    q0 += __shfl_xor(q0, 1); q0 += __shfl_xor(q0, 2); q0 += __shfl_xor(q0, 4); q0 += __shfl_xor(q0, 8);
    m0 += __shfl_xor(m0, 1); m0 += __shfl_xor(m0, 2); m0 += __shfl_xor(m0, 4); m0 += __shfl_xor(m0, 8);
    q1 += __shfl_xor(q1, 1); q1 += __shfl_xor(q1, 2); q1 += __shfl_xor(q1, 4); q1 += __shfl_xor(q1, 8);
    m1 += __shfl_xor(m1, 1); m1 += __shfl_xor(m1, 2); m1 += __shfl_xor(m1, 4); m1 += __shfl_xor(m1, 8);
    aq0 = q0; am0 = m0; aq1 = q1; am1 = m1;
  };
  auto s2core = [&](int index, int dstSlot) {
    const float4* W  = ((const float4*)smem) + ig * 384;
    const float4* h0 = (const float4*)(smem + SM_ST);
    const float4* h1 = (const float4*)(smem + SM_ST + 512);
    float gr0 = 0.f, gz0 = 0.f, gn0 = 0.f, gr1 = 0.f, gz1 = 0.f, gn1 = 0.f;
    #pragma unroll
    for (int t = 0; t < 8; ++t) {
      int k4 = t * 16 + l;
      float4 hv0 = h0[k4], hv1 = h1[k4];
      float4 a0 = W[k4], a1 = W[128 + k4], a2 = W[256 + k4];
      gr0 = fmaf(a0.x, hv0.x, gr0); gr0 = fmaf(a0.y, hv0.y, gr0); gr0 = fmaf(a0.z, hv0.z, gr0); gr0 = fmaf(a0.w, hv0.w, gr0);
      gz0 = fmaf(a1.x, hv0.x, gz0); gz0 = fmaf(a1.y, hv0.y, gz0); gz0 = fmaf(a1.z, hv0.z, gz0); gz0 = fmaf(a1.w, hv0.w, gz0);
      gn0 = fmaf(a2.x, hv0.x, gn0); gn0 = fmaf(a2.y, hv0.y, gn0); gn0 = fmaf(a2.z, hv0.z, gn0); gn0 = fmaf(a2.w, hv0.w, gn0);
      gr1 = fmaf(a0.x, hv1.x, gr1); gr1 = fmaf(a0.y, hv1.y, gr1); gr1 = fmaf(a0.z, hv1.z, gr1); gr1 = fmaf(a0.w, hv1.w, gr1);
      gz1 = fmaf(a1.x, hv1.x, gz1); gz1 = fmaf(a1.y, hv1.y, gz1); gz1 = fmaf(a1.z, hv1.z, gz1); gz1 = fmaf(a1.w, hv1.w, gz1);
      gn1 = fmaf(a2.x, hv1.x, gn1); gn1 = fmaf(a2.y, hv1.y, gn1); gn1 = fmaf(a2.z, hv1.z, gn1); gn1 = fmaf(a2.w, hv1.w, gn1);
    }
    gr0 += __shfl_xor(gr0, 1); gr0 += __shfl_xor(gr0, 2); gr0 += __shfl_xor(gr0, 4); gr0 += __shfl_xor(gr0, 8);
    gz0 += __shfl_xor(gz0, 1); gz0 += __shfl_xor(gz0, 2); gz0 += __shfl_xor(gz0, 4); gz0 += __shfl_xor(gz0, 8);
    gn0 += __shfl_xor(gn0, 1); gn0 += __shfl_xor(gn0, 2); gn0 += __shfl_xor(gn0, 4); gn0 += __shfl_xor(gn0, 8);
    gr1 += __shfl_xor(gr1, 1); gr1 += __shfl_xor(gr1, 2); gr1 += __shfl_xor(gr1, 4); gr1 += __shfl_xor(gr1, 8);
    gz1 += __shfl_xor(gz1, 1); gz1 += __shfl_xor(gz1, 2); gz1 += __shfl_xor(gz1, 4); gz1 += __shfl_xor(gz1, 8);
    gn1 += __shfl_xor(gn1, 1); gn1 += __shfl_xor(gn1, 2); gn1 += __shfl_xor(gn1, 4); gn1 += __shfl_xor(gn1, 8);
    if (l < 2) {
      int b = l;
      float gr = l ? gr1 : gr0, gz = l ? gz1 : gz0, gn = l ? gn1 : gn0;
      float h  = smem[SM_ST + b * 512 + i];
      const int gb2 = SM_GIS + ((b * 16 + index) * 3) * 16 + ig;
      float rr = sigf(smem[gb2 + 0]  + gr + smem[SM_BHH + 0 + ig]);
      float uu = sigf(smem[gb2 + 16] + gz + smem[SM_BHH + 16 + ig]);
      float nn = tanhf_(smem[gb2 + 32] + rr * (gn + smem[SM_BHH + 32 + ig]));
      float v = (1.f - uu) * nn + uu * h;
      if (i >= Hc) v = 0.f;
      stgf(wsf + hslotf(2 * g + b, dstSlot) + i, v);
    }
  };

  // ===== phase 0: hv(idx0) = GRU(x0, gs0) — gs0 already in SM_ST =====
  s2core(0, 0);
  flagbar();

  // ===== scan =====
  for (int index = 1; index < 16; ++index) {
    stage2v(hslotf(2 * g,     trif(index - 1) + index - 1),
            hslotf(2 * g + 1, trif(index - 1) + index - 1));
    if (tid < 32) {
      int b = tid >> 4, j = tid & 15;
      smem[SM_DEP + b * 16 + j] = dep[((size_t)(2 * g + b) * 16 + index) * 16 + j];
    }
    __syncthreads();
    {
      float aq0, am0, aq1, am1;
      s1core(aq0, am0, aq1, am1);
      if (l < 2) {
        float aq = l ? aq1 : aq0, am = l ? am1 : am0;
        smem[SM_QM + ((l * 2 + 0) * 15 + (index - 1)) * 16 + ig] = aq + smem[SM_GC + ig * 16 + (index - 1)];
        smem[SM_QM + ((l * 2 + 1) * 15 + (index - 1)) * 16 + ig] = am + smem[SM_GC + 256 + ig * 16 + (index - 1)];
      }
    }
    __syncthreads();
    if (l < 2) {               // PS backward cumsum, b = l
      float acc = 0.f, gb = smem[SM_GB + ig], mb = smem[SM_MB + ig];
      for (int j = 15; j >= 0; --j) {
        if (j != index) {
          float aa = smem[SM_DEP + l * 16 + j];
          float q, mm;
          if (j < index) { q = smem[SM_QM + ((l * 2 + 0) * 15 + j) * 16 + ig];
                           mm = smem[SM_QM + ((l * 2 + 1) * 15 + j) * 16 + ig]; }
          else           { q = smem[SM_GC + ig * 16 + j];
                           mm = smem[SM_GC + 256 + ig * 16 + j]; }
          float sg = sigf(fmaf(aa, q, gb));
          acc = fmaf(aa * sg, fmaf(aa, mm, mb), acc);
        }
        smem[SM_PS + (l * 16 + ig) * 16 + j] = acc;
      }
    } else if (l < 4) {        // hv0 = gru(x,0), b = l-2
      int b = l - 2;
      const int gb2 = SM_GIS + ((b * 16 + index) * 3) * 16 + ig;
      float rr = sigf(smem[gb2 + 0]  + smem[SM_BHH + 0 + ig]);
      float uu = sigf(smem[gb2 + 16] + smem[SM_BHH + 16 + ig]);
      float nn = tanhf_(smem[gb2 + 32] + rr * smem[SM_BHH + 32 + ig]);
      float v = (1.f - uu) * nn;
      if (i >= Hc) v = 0.f;
      stgf(wsf + hslotf(2 * g + b, trif(index) + 0) + i, v);
    }
    __syncthreads();
    if (l < 2) {               // h_in(s=0)
      int b = l;
      float gb = smem[SM_GB + ig], mb = smem[SM_MB + ig];
      float aI = smem[SM_DEP + b * 16 + index];
      float Qi = smem[SM_GC + ig * 16 + index], Mi = smem[SM_GC + 256 + ig * 16 + index];
      float f = aI * sigf(fmaf(aI, Qi, gb)) * fmaf(aI, Mi, mb);
      float v = smem[SM_PS + (b * 16 + ig) * 16 + (index - 1)] + f;
      if (i >= Hc) v = 0.f;
      stgf(wsf + OFF_HINS + ((size_t)(index * (index - 1) / 2 + 0) * 16 + (2 * g + b)) * 512 + i, v);
    }
    flagbar();

    for (int s = 0; s < index; ++s) {
      stage2v(OFF_HINS + ((size_t)(index * (index - 1) / 2 + s) * 16 + (2 * g + 0)) * 512,
              OFF_HINS + ((size_t)(index * (index - 1) / 2 + s) * 16 + (2 * g + 1)) * 512);
      __syncthreads();
      s2core(index, trif(index) + s + 1);
      flagbar();
      if (s + 1 < index) {
        int ss = s + 1, vj = index - 1 - ss;
        stage2v(hslotf(2 * g, trif(index) + ss), hslotf(2 * g + 1, trif(index) + ss));
        __syncthreads();
        {
          float aq0, am0, aq1, am1;
          s1core(aq0, am0, aq1, am1);
          if (l < 2) {
            int b = l;
            float aq = l ? aq1 : aq0, am = l ? am1 : am0;
            float gb = smem[SM_GB + ig], mb = smem[SM_MB + ig];
            float aI = smem[SM_DEP + b * 16 + index];
            float Qi = aq + smem[SM_GC + ig * 16 + index];
            float Mi = am + smem[SM_GC + 256 + ig * 16 + index];
            float f = aI * sigf(fmaf(aI, Qi, gb)) * fmaf(aI, Mi, mb);
            float v = smem[SM_PS + (b * 16 + ig) * 16 + vj] + f;
            if (i >= Hc) v = 0.f;
            stgf(wsf + OFF_HINS + ((size_t)(index * (index - 1) / 2 + ss) * 16 + (2 * g + b)) * 512 + i, v);
          }
        }
        flagbar();
      }
    }
  }
}

// ================= k2: deferred edges + node encodings — 512 blocks (2/CU) ==========
__global__ __launch_bounds__(256, 1) void k2_fin(KArgs a) {
  const int blk = blockIdx.x, tid = threadIdx.x;
  float* wsf = a.wsf;
  unsigned* FLG = (unsigned*)a.wsf + WS_FLOATS;
  unsigned* F1F = FLG + N_FLG;
  const float* ae1w = a.in[9];   // [2004][1002] cached
  const float* av1w = a.in[5];   // [1002][501]

  __shared__ float smem[F_TOT];
  const int b = blk >> 5, rs = blk & 31;
  const int il = tid >> 3, l8 = tid & 7;
  float4* lds4 = (float4*)smem;

  // ---- F1a staging: 16 nhs finals (row 15 zero) ----
  for (int t = tid; t < 2048; t += 256) {
    int j = t >> 7, k4 = t & 127;
    float4 v = {0.f, 0.f, 0.f, 0.f};
    if (j < 15) v = maskpad(((const float4*)(wsf + hslotf(b, trif(j) + j)))[k4], k4);
    lds4[t] = v;
  }
  __syncthreads();
  // ---- prefetch F1b staging into registers ----
  float4 pfb[8];
  #pragma unroll
  for (int p = 0; p < 8; ++p) {
    int fidx = p * 256 + tid, idx = fidx >> 7, k4 = fidx & 127;
    const float4* src = (idx == 0)
      ? ((const float4*)(wsf + OFF_GS0 + (size_t)b * 512))
      : ((const float4*)(wsf + hslotf(b, trif(idx - 1) + idx - 1)));
    pfb[p] = maskpad(src[k4], k4);
  }
  // ---- F1a compute: Bhj = ae1w[:,501:] @ nhs_j  (63 rows/block) ----
  {
    const int rbase = rs * 63 + il * 2;
    int rq[2];
    #pragma unroll
    for (int q = 0; q < 2; ++q) rq[q] = mini(rbase + q, 2003);
    for (int half = 0; half < 2; ++half) {
      int jbase = half * 8;
      float acc[2][8];
      #pragma unroll
      for (int q = 0; q < 2; ++q)
        #pragma unroll
        for (int j = 0; j < 8; ++j) acc[q][j] = 0.f;
      for (int s = 0; s < 63; ++s) {
        int k = s * 8 + l8;
        int kc = (k > 500) ? 500 : k;
        float w[2];
        #pragma unroll
        for (int q = 0; q < 2; ++q) w[q] = ae1w[(size_t)rq[q] * 1002 + 501 + kc];
        float hv[8];
        #pragma unroll
        for (int j = 0; j < 8; ++j) hv[j] = smem[(jbase + j) * 512 + k];
        #pragma unroll
        for (int q = 0; q < 2; ++q)
          #pragma unroll
          for (int j = 0; j < 8; ++j) acc[q][j] = fmaf(w[q], hv[j], acc[q][j]);
      }
      #pragma unroll
      for (int q = 0; q < 2; ++q) {
        bool rowok = (il * 2 + q < 63) && (rbase + q < 2004);
        #pragma unroll
        for (int j = 0; j < 8; ++j) {
          float v = acc[q][j];
          v += __shfl_xor(v, 1); v += __shfl_xor(v, 2); v += __shfl_xor(v, 4);
          if (l8 == 0 && rowok && (jbase + j) < 15)
            smem[F_BHJ + (jbase + j) * 64 + il * 2 + q] = v;
        }
      }
    }
  }
  __syncthreads();
  // ---- F1b staging from registers ----
  #pragma unroll
  for (int p = 0; p < 8; ++p) lds4[p * 256 + tid] = pfb[p];
  __syncthreads();
  // ---- F1b compute: TBUF = relu(av1w @ gs-list + b)  (32 rows/block, 1/il) ----
  {
    const float* av1b = a.in[6];
    const int r = rs * 32 + il;
    const int rc = mini(r, 1001);
    for (int half = 0; half < 2; ++half) {
      int jbase = half * 8;
      float acc[8];
      #pragma unroll
      for (int j = 0; j < 8; ++j) acc[j] = 0.f;
      for (int s = 0; s < 63; ++s) {
        int k = s * 8 + l8;
        int kc = (k > 500) ? 500 : k;
        float w = av1w[(size_t)rc * 501 + kc];
        #pragma unroll
        for (int j = 0; j < 8; ++j) acc[j] = fmaf(w, smem[(jbase + j) * 512 + k], acc[j]);
      }
      bool rowok = (r < 1002);
      float b1 = rowok ? av1b[r] : 0.f;
      #pragma unroll
      for (int j = 0; j < 8; ++j) {
        float v = acc[j];
        v += __shfl_xor(v, 1); v += __shfl_xor(v, 2); v += __shfl_xor(v, 4);
        if (l8 == 0 && rowok)
          stgf(wsf + OFF_TBUF + ((size_t)b * 16 + jbase + j) * 1024 + r, fmaxf(v + b1, 0.f));
      }
    }
  }
  __syncthreads();
  if (tid == 0)
    __hip_atomic_store(F1F + b * 32 + rs, 1u, __ATOMIC_RELAXED, __HIP_MEMORY_SCOPE_AGENT);

  // ---- F2: 120 edges, double-buffered chunk staging (63 rows/block) ----
  const float* ae1b = a.in[10]; const float* ae2w = a.in[11]; const float* ae2b = a.in[12];
  const int rbase = rs * 63 + il * 2;
  int rq[2];
  #pragma unroll
  for (int q = 0; q < 2; ++q) rq[q] = mini(rbase + q, 2003);
  auto decode = [&](int chunk, int* idxs, int* vjs, bool* tval) {
    #pragma unroll
    for (int j = 0; j < 8; ++j) {
      int e = chunk * 8 + j;
      if (e < 120) {
        int ix = 1, rem = e;
        while (rem >= ix) { rem -= ix; ++ix; }
        idxs[j] = ix; vjs[j] = rem; tval[j] = true;
      } else { idxs[j] = 1; vjs[j] = 0; tval[j] = false; }
    }
  };
  {
    int idxs[8], vjs[8]; bool tval[8];
    decode(0, idxs, vjs, tval);
    for (int t = tid; t < 1024; t += 256) {
      int sl = t >> 7, k4 = t & 127;
      int sE = idxs[sl] - 1 - vjs[sl];
      lds4[t] = maskpad(((const float4*)(wsf + hslotf(b, trif(idxs[sl]) + sE)))[k4], k4);
    }
  }
  __syncthreads();
  int cur = 0;
  for (int chunk = 0; chunk < 15; ++chunk) {
    int idxs[8], vjs[8]; bool tval[8];
    decode(chunk, idxs, vjs, tval);
    float4 pf[4];
    if (chunk < 14) {
      int nidxs[8], nvjs[8]; bool ntval[8];
      decode(chunk + 1, nidxs, nvjs, ntval);
      #pragma unroll
      for (int p = 0; p < 4; ++p) {
        int fidx = p * 256 + tid, sl = fidx >> 7, k4 = fidx & 127;
        int sE = nidxs[sl] - 1 - nvjs[sl];
        pf[p] = maskpad(((const float4*)(wsf + hslotf(b, trif(nidxs[sl]) + sE)))[k4], k4);
      }
    }
    const float* hbuf = smem + cur * 4096;
    float acc[2][8];
    #pragma unroll
    for (int q = 0; q < 2; ++q)
      #pragma unroll
      for (int j = 0; j < 8; ++j) acc[q][j] = 0.f;
    for (int s = 0; s < 63; ++s) {
      int k = s * 8 + l8;
      int kc = (k > 500) ? 500 : k;
      float w[2];
      #pragma unroll
      for (int q = 0; q < 2; ++q) w[q] = ae1w[(size_t)rq[q] * 1002 + kc];
      float hv[8];
      #pragma unroll
      for (int j = 0; j < 8; ++j) hv[j] = hbuf[j * 512 + k];
      #pragma unroll
      for (int q = 0; q < 2; ++q)
        #pragma unroll
        for (int j = 0; j < 8; ++j) acc[q][j] = fmaf(w[q], hv[j], acc[q][j]);
    }
    float part[8];
    #pragma unroll
    for (int j = 0; j < 8; ++j) part[j] = 0.f;
    #pragma unroll
    for (int q = 0; q < 2; ++q) {
      int r = rbase + q;
      bool rowok = (il * 2 + q < 63) && (r < 2004);
      float aer = rowok ? ae2w[r] : 0.f;
      float b1r = rowok ? ae1b[r] : 0.f;
      #pragma unroll
      for (int j = 0; j < 8; ++j) {
        float v = acc[q][j];
        v += __shfl_xor(v, 1); v += __shfl_xor(v, 2); v += __shfl_xor(v, 4);
        if (l8 == 0 && rowok && tval[j]) {
          float bh = smem[F_BHJ + vjs[j] * 64 + il * 2 + q];
          part[j] = fmaf(aer, fmaxf(v + bh + b1r, 0.f), part[j]);
        }
      }
    }
    if (l8 == 0) {
      #pragma unroll
      for (int j = 0; j < 8; ++j) smem[F_RED + il * 8 + j] = part[j];
    }
    __syncthreads();
    if (tid < 8) {
      float v = 0.f;
      for (int q = 0; q < 32; ++q) v += smem[F_RED + q * 8 + tid];
      if (rs == 0) v += ae2b[0];
      if (tval[tid])
        atomicAdd(a.out + ((size_t)b * 16 + idxs[tid]) * 16 + vjs[tid], v);
    }
    __syncthreads();
    if (chunk < 14) {
      #pragma unroll
      for (int p = 0; p < 4; ++p) lds4[(1 - cur) * 1024 + p * 256 + tid] = pf[p];
      cur = 1 - cur;
      __syncthreads();
    }
  }
  // ---- F3: gen_node_encoding[(b, rs)] — only rs<16 blocks ----
  if (rs < 16) {
    if (tid < 32) {
      unsigned* p = F1F + b * 32 + tid;
      while (__hip_atomic_load(p, __ATOMIC_RELAXED, __HIP_MEMORY_SCOPE_AGENT) != 1u)
        __builtin_amdgcn_s_sleep(2);
    }
    __syncthreads();
    const float* av2w = a.in[7]; const float* av2b = a.in[8];
    const float* tb = wsf + OFF_TBUF + ((size_t)b * 16 + rs) * 1024;
    float accn[10];
    #pragma unroll
    for (int c = 0; c < 10; ++c) accn[c] = 0.f;
    for (int r = tid; r < 1002; r += 256) {
      float tv = tb[r];
      #pragma unroll
      for (int c = 0; c < 10; ++c) accn[c] = fmaf(av2w[(size_t)c * 1002 + r], tv, accn[c]);
    }
    #pragma unroll
    for (int c = 0; c < 10; ++c) {
      float v = accn[c];
      for (int m2 = 1; m2 < 64; m2 <<= 1) v += __shfl_xor(v, m2);
      if ((tid & 63) == 0) smem[F_RED + (tid >> 6) * 10 + c] = v;
    }
    __syncthreads();
    if (tid == 0) {
      for (int c = 0; c < 10; ++c) {
        float v = av2b[c] + smem[F_RED + c] + smem[F_RED + 10 + c] + smem[F_RED + 20 + c] + smem[F_RED + 30 + c];
        stgf(a.out + 4096 + ((size_t)b * 16 + rs) * 10 + c, v);
      }
    }
  }
}

extern "C" void kernel_launch(void* const* d_in, const int* in_sizes, int n_in,
                              void* d_out, int out_size, void* d_ws, size_t ws_size,
                              hipStream_t stream) {
  (void)in_sizes; (void)n_in; (void)out_size;
  if (ws_size < WS_NEED) return;   // fail loudly via validation
  KArgs a;
  for (int k = 0; k < 21; ++k) a.in[k] = (const float*)d_in[k];
  a.out = (float*)d_out;
  a.wsf = (float*)d_ws;
  k0_init<<<64, 256, 0, stream>>>(a);
  k1_scan<<<256, 256, 0, stream>>>(a);
  k2_fin <<<512, 256, 0, stream>>>(a);
}